// Round 17
// baseline (530.518 us; speedup 1.0000x reference)
//
#include <hip/hip_runtime.h>

#define N_SRC 50000
#define N_DST1 20000
#define N_DST2 10000
#define E1 320000
#define E2 160000
#define T 12
#define C_IN 64
#define HID 16
#define C_OUT 32
#define TB 782      // transform blocks per t: ceil(50000/64)
#define HB 15       // histogram blocks: 10x2000 bins (L1) + 5x2000 (L2)

__device__ __forceinline__ float lrelu(float x, float s) { return x > 0.f ? x : s * x; }

// Bijective XCD-aware swizzle: XCD x = p%8 owns a contiguous logical chunk.
__device__ __forceinline__ int xcd_swizzle(int p, int W) {
    int x = p & 7, k = p >> 3;
    int q = W >> 3, r = W & 7;
    return (x < r ? x * (q + 1) : r * (q + 1) + (x - r) * q) + k;
}

// ---------------- k_pre: [15 region-hist blocks] || [transform, 12 t] ----
// Hist blocks: block b owns 2000 bins; reads the whole dst array (L2
// broadcast), LDS histogram (reuses xs region), direct store -> no global
// atomics, no pre-zeroing, k_zero+k_hist nodes deleted.
__global__ __launch_bounds__(256) void k_pre(
    const int* __restrict__ d1, const int* __restrict__ d2,
    int* __restrict__ cnt1, int* __restrict__ cnt2,
    const float* __restrict__ nf, const float* __restrict__ W1,
    const float* __restrict__ a_l, const float* __restrict__ a_r,
    float* __restrict__ hs1, float* __restrict__ el1, float* __restrict__ er1)
{
    __shared__ float xs[64][68];
    __shared__ float w[C_IN][HID];
    __shared__ float al[HID], ar[HID];
    int tx = threadIdx.x;

    if (blockIdx.x < HB) {
        int* hist = (int*)&xs[0][0];          // 8KB inside the 17.4KB xs
        int b = blockIdx.x;
        const int* dsrc; int E, lo; int* cnt;
        if (b < 10) { dsrc = d1; E = E1; lo = b * 2000; cnt = cnt1; }
        else        { dsrc = d2; E = E2; lo = (b - 10) * 2000; cnt = cnt2; }
        for (int i = tx; i < 2000; i += 256) hist[i] = 0;
        __syncthreads();
        for (int e = tx; e < E; e += 256) {
            int d = dsrc[e] - lo;
            if ((unsigned)d < 2000u) atomicAdd(&hist[d], 1);
        }
        __syncthreads();
        for (int i = tx; i < 2000; i += 256) cnt[lo + i] = hist[i];
        return;
    }

    int idx = blockIdx.x - HB;
    int nblk = idx % TB;
    int t = idx / TB;
    int n0 = nblk * 64;
    int nrem = N_SRC - n0; if (nrem > 64) nrem = 64;

    reinterpret_cast<float4*>(&w[0][0])[tx] = reinterpret_cast<const float4*>(W1)[tx];
    if (tx < HID) al[tx] = a_l[tx];
    else if (tx < 2 * HID) ar[tx - HID] = a_r[tx - HID];

    const float4* gp = reinterpret_cast<const float4*>(nf + ((size_t)t * N_SRC + n0) * C_IN);
#pragma unroll
    for (int k = 0; k < 4; k++) {
        int f = k * 256 + tx;
        int node = f >> 4;
        if (node < nrem)
            *reinterpret_cast<float4*>(&xs[node][(f & 15) * 4]) = gp[f];
    }
    __syncthreads();

    int q = tx & 3;
    int nn = tx >> 2;
    float4 acc = make_float4(0.f, 0.f, 0.f, 0.f);
#pragma unroll
    for (int c4 = 0; c4 < 16; c4++) {
        float4 xA = *reinterpret_cast<const float4*>(&xs[nn][c4 * 4]);
        float4 w0 = *reinterpret_cast<const float4*>(&w[c4 * 4 + 0][q * 4]);
        float4 w1 = *reinterpret_cast<const float4*>(&w[c4 * 4 + 1][q * 4]);
        float4 w2 = *reinterpret_cast<const float4*>(&w[c4 * 4 + 2][q * 4]);
        float4 w3 = *reinterpret_cast<const float4*>(&w[c4 * 4 + 3][q * 4]);
        acc.x += xA.x * w0.x + xA.y * w1.x + xA.z * w2.x + xA.w * w3.x;
        acc.y += xA.x * w0.y + xA.y * w1.y + xA.z * w2.y + xA.w * w3.y;
        acc.z += xA.x * w0.z + xA.y * w1.z + xA.z * w2.z + xA.w * w3.z;
        acc.w += xA.x * w0.w + xA.y * w1.w + xA.z * w2.w + xA.w * w3.w;
    }

    float el = acc.x * al[q * 4] + acc.y * al[q * 4 + 1] + acc.z * al[q * 4 + 2] + acc.w * al[q * 4 + 3];
    float er = acc.x * ar[q * 4] + acc.y * ar[q * 4 + 1] + acc.z * ar[q * 4 + 2] + acc.w * ar[q * 4 + 3];
    el += __shfl_xor(el, 1); el += __shfl_xor(el, 2);
    er += __shfl_xor(er, 1); er += __shfl_xor(er, 2);

    if (nn < nrem) {
        float* hb = hs1 + ((size_t)t * N_SRC + n0) * HID;
        *reinterpret_cast<float4*>(hb + (size_t)nn * HID + q * 4) = acc;
        if (q == 0) {
            int n = n0 + nn;
            el1[(size_t)t * N_SRC + n] = el;
            if (n < N_DST1) er1[(size_t)t * N_DST1 + n] = er;
        }
    }
}

// ---------------- scan (+wvec) ------------------------------------------
__device__ void scan_one(const int* cnt, int* off, int* cur, int N)
{
    __shared__ int part[1024];
    int tx = threadIdx.x;
    int CH = (N + 1023) / 1024;
    int base = tx * CH;
    int p = 0;
    for (int k = 0; k < CH; k++) { int i = base + k; if (i < N) p += cnt[i]; }
    part[tx] = p;
    __syncthreads();
#pragma unroll
    for (int d = 1; d < 1024; d <<= 1) {
        int v = (tx >= d) ? part[tx - d] : 0;
        __syncthreads();
        part[tx] += v;
        __syncthreads();
    }
    int run = (tx == 0) ? 0 : part[tx - 1];
    if (tx == 0) off[0] = 0;
    for (int k = 0; k < CH; k++) {
        int i = base + k;
        if (i < N) { cur[i] = run; run += cnt[i]; off[i + 1] = run; }
    }
}

__global__ __launch_bounds__(1024) void k_scan(
    const int* __restrict__ cnt1, int* __restrict__ off1, int* __restrict__ cur1,
    const int* __restrict__ cnt2, int* __restrict__ off2, int* __restrict__ cur2,
    const float* __restrict__ W2, const float* __restrict__ al2,
    const float* __restrict__ ar2, float* __restrict__ wl2, float* __restrict__ wr2)
{
    if (blockIdx.x == 2) {
        int tx = threadIdx.x;
        if (tx < 32) {
            int c = tx & 15;
            const float* a = (tx < 16) ? al2 : ar2;
            float s = 0.f;
            for (int o = 0; o < C_OUT; o++) s += W2[c * C_OUT + o] * a[o];
            if (tx < 16) wl2[c] = s; else wr2[c] = s;
        }
        return;
    }
    if (blockIdx.x == 0) scan_one(cnt1, off1, cur1, N_DST1);
    else                 scan_one(cnt2, off2, cur2, N_DST2);
}

__global__ __launch_bounds__(256) void k_scatter(
    const int* __restrict__ s1, const int* __restrict__ d1, const float* __restrict__ w1,
    int* __restrict__ cur1, int2* __restrict__ sw1,
    const int* __restrict__ s2, const int* __restrict__ d2, const float* __restrict__ w2,
    int* __restrict__ cur2, int2* __restrict__ sw2)
{
    int e = blockIdx.x * 256 + threadIdx.x;
    if (e < E1) {
        int d = d1[e];
        int p = atomicAdd(&cur1[d], 1);
        sw1[p] = make_int2(s1[e], __float_as_int(w1[e]));
    } else if (e < E1 + E2) {
        int ee = e - E1;
        int d = d2[ee];
        int p = atomicAdd(&cur2[d], 1);
        sw2[p] = make_int2(s2[ee], __float_as_int(w2[ee]));
    }
}

// ---------------- fused GAT layer: 16 lanes per (dst,t) -----------------
// 4/2/1 independent gather chains. No max shift (logits bounded ~[-1,4]).
#define EDGE1(I)                                                                \
    {                                                                           \
        int2 sa = sw[I];                                                        \
        float ea = elb[sa.x];                                                   \
        float4 ha = *reinterpret_cast<const float4*>(hsb + (size_t)sa.x * HID + q * 4); \
        float exa = __expf(lrelu(ea + erv, 0.2f));                              \
        den += exa;                                                             \
        float ca = exa * __int_as_float(sa.y);                                  \
        num.x += ca * ha.x; num.y += ca * ha.y;                                 \
        num.z += ca * ha.z; num.w += ca * ha.w;                                 \
    }

template <int NDST, int NSRC, bool FINAL>
__global__ __launch_bounds__(256) void k_gat(
    const int* __restrict__ off, const int2* __restrict__ sw,
    const float* __restrict__ el, const float* __restrict__ er,
    const float* __restrict__ hs, float* __restrict__ outp,
    const float* __restrict__ wl, const float* __restrict__ wr,
    float* __restrict__ el_out, float* __restrict__ er_out)
{
    __shared__ float w2s[FINAL ? HID * C_OUT : 1];
    int tx = threadIdx.x;
    if (FINAL) {
        for (int idx = tx; idx < HID * C_OUT; idx += 256) w2s[idx] = wl[idx];
        __syncthreads();
    }
    int wblk = xcd_swizzle(blockIdx.x, (NDST * T) / 16);
    int grp = tx >> 4;
    int lane16 = tx & 15;
    int q = lane16 & 3;
    int eslot = lane16 >> 2;
    int g = wblk * 16 + grp;       // t*NDST + d
    int t = g / NDST;
    int d = g - t * NDST;
    int start = off[d], end = off[d + 1];
    float erv = er[g];
    const float* elb = el + (size_t)t * NSRC;
    const float* hsb = hs + (size_t)t * NSRC * HID;

    float4 num = make_float4(0.f, 0.f, 0.f, 0.f);
    float den = 0.f;
    int i = start + eslot;
    for (; i + 12 < end; i += 16) {
        int2 sa = sw[i];
        int2 sb = sw[i + 4];
        int2 sc = sw[i + 8];
        int2 sd = sw[i + 12];
        float ea = elb[sa.x];
        float eb = elb[sb.x];
        float ec = elb[sc.x];
        float ed = elb[sd.x];
        float4 ha = *reinterpret_cast<const float4*>(hsb + (size_t)sa.x * HID + q * 4);
        float4 hb = *reinterpret_cast<const float4*>(hsb + (size_t)sb.x * HID + q * 4);
        float4 hc = *reinterpret_cast<const float4*>(hsb + (size_t)sc.x * HID + q * 4);
        float4 hd = *reinterpret_cast<const float4*>(hsb + (size_t)sd.x * HID + q * 4);
        float exa = __expf(lrelu(ea + erv, 0.2f));
        float exb = __expf(lrelu(eb + erv, 0.2f));
        float exc = __expf(lrelu(ec + erv, 0.2f));
        float exd = __expf(lrelu(ed + erv, 0.2f));
        den += (exa + exb) + (exc + exd);
        float ca = exa * __int_as_float(sa.y);
        float cb = exb * __int_as_float(sb.y);
        float cc = exc * __int_as_float(sc.y);
        float cd = exd * __int_as_float(sd.y);
        num.x += ca * ha.x + cb * hb.x + cc * hc.x + cd * hd.x;
        num.y += ca * ha.y + cb * hb.y + cc * hc.y + cd * hd.y;
        num.z += ca * ha.z + cb * hb.z + cc * hc.z + cd * hd.z;
        num.w += ca * ha.w + cb * hb.w + cc * hc.w + cd * hd.w;
    }
    for (; i + 4 < end; i += 8) {
        int2 sa = sw[i];
        int2 sb = sw[i + 4];
        float ea = elb[sa.x];
        float eb = elb[sb.x];
        float4 ha = *reinterpret_cast<const float4*>(hsb + (size_t)sa.x * HID + q * 4);
        float4 hb = *reinterpret_cast<const float4*>(hsb + (size_t)sb.x * HID + q * 4);
        float exa = __expf(lrelu(ea + erv, 0.2f));
        float exb = __expf(lrelu(eb + erv, 0.2f));
        den += exa + exb;
        float ca = exa * __int_as_float(sa.y);
        float cb = exb * __int_as_float(sb.y);
        num.x += ca * ha.x + cb * hb.x;
        num.y += ca * ha.y + cb * hb.y;
        num.z += ca * ha.z + cb * hb.z;
        num.w += ca * ha.w + cb * hb.w;
    }
    if (i < end) EDGE1(i);
#pragma unroll
    for (int mk = 4; mk <= 8; mk <<= 1) {
        num.x += __shfl_xor(num.x, mk);
        num.y += __shfl_xor(num.y, mk);
        num.z += __shfl_xor(num.z, mk);
        num.w += __shfl_xor(num.w, mk);
        den   += __shfl_xor(den, mk);
    }
    float inv = 1.f / (den + 1e-9f);
    float4 v = make_float4(num.x * inv, num.y * inv, num.z * inv, num.w * inv);

    if (!FINAL) {
        v.x = lrelu(v.x, 0.01f); v.y = lrelu(v.y, 0.01f);
        v.z = lrelu(v.z, 0.01f); v.w = lrelu(v.w, 0.01f);
        if (eslot == 0) {
            *reinterpret_cast<float4*>(outp + (size_t)g * HID + q * 4) = v;
            float pl = v.x * wl[q * 4] + v.y * wl[q * 4 + 1] + v.z * wl[q * 4 + 2] + v.w * wl[q * 4 + 3];
            float pr = v.x * wr[q * 4] + v.y * wr[q * 4 + 1] + v.z * wr[q * 4 + 2] + v.w * wr[q * 4 + 3];
            pl += __shfl_xor(pl, 1); pl += __shfl_xor(pl, 2);
            pr += __shfl_xor(pr, 1); pr += __shfl_xor(pr, 2);
            if (q == 0) {
                el_out[g] = pl;
                if (d < N_DST2) er_out[(size_t)t * N_DST2 + d] = pr;
            }
        }
    } else {
        float4 v1, v2, v3;
        v1.x = __shfl_xor(v.x, 1); v1.y = __shfl_xor(v.y, 1); v1.z = __shfl_xor(v.z, 1); v1.w = __shfl_xor(v.w, 1);
        v2.x = __shfl_xor(v.x, 2); v2.y = __shfl_xor(v.y, 2); v2.z = __shfl_xor(v.z, 2); v2.w = __shfl_xor(v.w, 2);
        v3.x = __shfl_xor(v.x, 3); v3.y = __shfl_xor(v.y, 3); v3.z = __shfl_xor(v.z, 3); v3.w = __shfl_xor(v.w, 3);
        int obase = q * 8;
        float out8[8];
#pragma unroll
        for (int oo = 0; oo < 8; oo++) out8[oo] = 0.f;
#define ACCQ(Q, R0)                                                             \
        {                                                                       \
            int r0 = (R0) * 4;                                                  \
            _Pragma("unroll")                                                   \
            for (int oo = 0; oo < 8; oo++)                                      \
                out8[oo] += (Q).x * w2s[(r0 + 0) * C_OUT + obase + oo]          \
                          + (Q).y * w2s[(r0 + 1) * C_OUT + obase + oo]          \
                          + (Q).z * w2s[(r0 + 2) * C_OUT + obase + oo]          \
                          + (Q).w * w2s[(r0 + 3) * C_OUT + obase + oo];         \
        }
        ACCQ(v,  q);
        ACCQ(v1, q ^ 1);
        ACCQ(v2, q ^ 2);
        ACCQ(v3, q ^ 3);
#undef ACCQ
        if (eslot == 0) {
            float* op = outp + (size_t)g * C_OUT + obase;
            float4 w0 = make_float4(lrelu(out8[0], 0.01f), lrelu(out8[1], 0.01f),
                                    lrelu(out8[2], 0.01f), lrelu(out8[3], 0.01f));
            float4 w1 = make_float4(lrelu(out8[4], 0.01f), lrelu(out8[5], 0.01f),
                                    lrelu(out8[6], 0.01f), lrelu(out8[7], 0.01f));
            *reinterpret_cast<float4*>(op) = w0;
            *reinterpret_cast<float4*>(op + 4) = w1;
        }
    }
}

extern "C" void kernel_launch(void* const* d_in, const int* in_sizes, int n_in,
                              void* d_out, int out_size, void* d_ws, size_t ws_size,
                              hipStream_t stream)
{
    const float* node_feat = (const float*)d_in[0];
    const int*   esrc1     = (const int*)d_in[1];
    const int*   edst1     = (const int*)d_in[2];
    const float* ew1       = (const float*)d_in[3];
    const int*   esrc2     = (const int*)d_in[4];
    const int*   edst2     = (const int*)d_in[5];
    const float* ew2       = (const float*)d_in[6];
    const float* W1        = (const float*)d_in[7];
    const float* a_l1      = (const float*)d_in[8];
    const float* a_r1      = (const float*)d_in[9];
    const float* W2        = (const float*)d_in[10];
    const float* a_l2      = (const float*)d_in[11];
    const float* a_r2      = (const float*)d_in[12];
    float* out = (float*)d_out;

    float* ws = (float*)d_ws;
    float* hs1 = ws;                        // 9,600,000  [T][N_SRC][16]
    float* el1 = hs1 + 9600000;             //   600,000  [T][N_SRC]
    float* er1 = el1 + 600000;              //   240,000  [T][N_DST1]
    float* h1  = er1 + 240000;              // 3,840,000  [T][N_DST1][16]
    float* el2 = h1 + 3840000;              //   240,000  [T][N_DST1]
    float* er2 = el2 + 240000;              //   120,000  [T][N_DST2]
    float* wl2 = er2 + 120000;              //        16
    float* wr2 = wl2 + 16;                  //        16
    int2* sw1 = (int2*)(wr2 + 16);          // E1 (16B-aligned)
    int2* sw2 = sw1 + E1;                   // E2
    int* cnt1 = (int*)(sw2 + E2);           //  20,000
    int* cnt2 = cnt1 + N_DST1;              //  10,000
    int* off1 = cnt2 + N_DST2;              //  20,001
    int* cur1 = off1 + N_DST1 + 1;          //  20,000
    int* off2 = cur1 + N_DST1;              //  10,001
    int* cur2 = off2 + N_DST2 + 1;          //  10,000

    k_pre<<<HB + TB * T, 256, 0, stream>>>(edst1, edst2, cnt1, cnt2,
                                           node_feat, W1, a_l1, a_r1, hs1, el1, er1);
    k_scan<<<3, 1024, 0, stream>>>(cnt1, off1, cur1, cnt2, off2, cur2,
                                   W2, a_l2, a_r2, wl2, wr2);
    k_scatter<<<(E1 + E2 + 255) / 256, 256, 0, stream>>>(
        esrc1, edst1, ew1, cur1, sw1,
        esrc2, edst2, ew2, cur2, sw2);
    k_gat<N_DST1, N_SRC, false><<<(N_DST1 * T) / 16, 256, 0, stream>>>(
        off1, sw1, el1, er1, hs1, h1, wl2, wr2, el2, er2);
    k_gat<N_DST2, N_DST1, true><<<(N_DST2 * T) / 16, 256, 0, stream>>>(
        off2, sw2, el2, er2, h1, out, W2, nullptr, nullptr, nullptr);
}

// Round 18
// 264.777 us; speedup vs baseline: 2.0036x; 2.0036x over previous
//
#include <hip/hip_runtime.h>

#define N_SRC 50000
#define N_DST1 20000
#define N_DST2 10000
#define E1 320000
#define E2 160000
#define T 12
#define C_IN 64
#define HID 16
#define C_OUT 32

__device__ __forceinline__ float lrelu(float x, float s) { return x > 0.f ? x : s * x; }

// Bijective XCD-aware swizzle: XCD x = p%8 owns a contiguous logical chunk.
__device__ __forceinline__ int xcd_swizzle(int p, int W) {
    int x = p & 7, k = p >> 3;
    int q = W >> 3, r = W & 7;
    return (x < r ? x * (q + 1) : r * (q + 1) + (x - r) * q) + k;
}

__global__ __launch_bounds__(256) void k_zero(int4* __restrict__ p, int n4)
{
    int i = blockIdx.x * 256 + threadIdx.x;
    if (i < n4) p[i] = make_int4(0, 0, 0, 0);
}

// ---------------- Layer-1 transform: 64-node tile, ~21.6KB LDS ----------
__global__ __launch_bounds__(256) void k_transform1(
    const float* __restrict__ nf, const float* __restrict__ W1,
    const float* __restrict__ a_l, const float* __restrict__ a_r,
    float* __restrict__ hs1, float* __restrict__ el1, float* __restrict__ er1)
{
    __shared__ float xs[64][68];
    __shared__ float w[C_IN][HID];
    __shared__ float al[HID], ar[HID];
    int tx = threadIdx.x;
    int t = blockIdx.y;
    int n0 = blockIdx.x * 64;
    int nrem = N_SRC - n0; if (nrem > 64) nrem = 64;

    reinterpret_cast<float4*>(&w[0][0])[tx] = reinterpret_cast<const float4*>(W1)[tx];
    if (tx < HID) al[tx] = a_l[tx];
    else if (tx < 2 * HID) ar[tx - HID] = a_r[tx - HID];

    const float4* gp = reinterpret_cast<const float4*>(nf + ((size_t)t * N_SRC + n0) * C_IN);
#pragma unroll
    for (int k = 0; k < 4; k++) {
        int f = k * 256 + tx;
        int node = f >> 4;
        if (node < nrem)
            *reinterpret_cast<float4*>(&xs[node][(f & 15) * 4]) = gp[f];
    }
    __syncthreads();

    int q = tx & 3;
    int nn = tx >> 2;
    float4 acc = make_float4(0.f, 0.f, 0.f, 0.f);
#pragma unroll
    for (int c4 = 0; c4 < 16; c4++) {
        float4 xA = *reinterpret_cast<const float4*>(&xs[nn][c4 * 4]);
        float4 w0 = *reinterpret_cast<const float4*>(&w[c4 * 4 + 0][q * 4]);
        float4 w1 = *reinterpret_cast<const float4*>(&w[c4 * 4 + 1][q * 4]);
        float4 w2 = *reinterpret_cast<const float4*>(&w[c4 * 4 + 2][q * 4]);
        float4 w3 = *reinterpret_cast<const float4*>(&w[c4 * 4 + 3][q * 4]);
        acc.x += xA.x * w0.x + xA.y * w1.x + xA.z * w2.x + xA.w * w3.x;
        acc.y += xA.x * w0.y + xA.y * w1.y + xA.z * w2.y + xA.w * w3.y;
        acc.z += xA.x * w0.z + xA.y * w1.z + xA.z * w2.z + xA.w * w3.z;
        acc.w += xA.x * w0.w + xA.y * w1.w + xA.z * w2.w + xA.w * w3.w;
    }

    float el = acc.x * al[q * 4] + acc.y * al[q * 4 + 1] + acc.z * al[q * 4 + 2] + acc.w * al[q * 4 + 3];
    float er = acc.x * ar[q * 4] + acc.y * ar[q * 4 + 1] + acc.z * ar[q * 4 + 2] + acc.w * ar[q * 4 + 3];
    el += __shfl_xor(el, 1); el += __shfl_xor(el, 2);
    er += __shfl_xor(er, 1); er += __shfl_xor(er, 2);

    if (nn < nrem) {
        float* hb = hs1 + ((size_t)t * N_SRC + n0) * HID;
        *reinterpret_cast<float4*>(hb + (size_t)nn * HID + q * 4) = acc;
        if (q == 0) {
            int n = n0 + nn;
            el1[(size_t)t * N_SRC + n] = el;
            if (n < N_DST1) er1[(size_t)t * N_DST1 + n] = er;
        }
    }
}

// ---------------- CSR build: parallel hist + scan (+wvec) ---------------
__global__ __launch_bounds__(256) void k_hist(
    const int* __restrict__ d1, const int* __restrict__ d2,
    int* __restrict__ cnt1, int* __restrict__ cnt2)
{
    int e = blockIdx.x * 256 + threadIdx.x;
    if (e < E1) atomicAdd(&cnt1[d1[e]], 1);
    else if (e < E1 + E2) atomicAdd(&cnt2[d2[e - E1]], 1);
}

__device__ void scan_one(const int* cnt, int* off, int* cur, int N)
{
    __shared__ int part[1024];
    int tx = threadIdx.x;
    int CH = (N + 1023) / 1024;
    int base = tx * CH;
    int p = 0;
    for (int k = 0; k < CH; k++) { int i = base + k; if (i < N) p += cnt[i]; }
    part[tx] = p;
    __syncthreads();
#pragma unroll
    for (int d = 1; d < 1024; d <<= 1) {
        int v = (tx >= d) ? part[tx - d] : 0;
        __syncthreads();
        part[tx] += v;
        __syncthreads();
    }
    int run = (tx == 0) ? 0 : part[tx - 1];
    if (tx == 0) off[0] = 0;
    for (int k = 0; k < CH; k++) {
        int i = base + k;
        if (i < N) { cur[i] = run; run += cnt[i]; off[i + 1] = run; }
    }
}

__global__ __launch_bounds__(1024) void k_scan(
    const int* __restrict__ cnt1, int* __restrict__ off1, int* __restrict__ cur1,
    const int* __restrict__ cnt2, int* __restrict__ off2, int* __restrict__ cur2,
    const float* __restrict__ W2, const float* __restrict__ al2,
    const float* __restrict__ ar2, float* __restrict__ wl2, float* __restrict__ wr2)
{
    if (blockIdx.x == 2) {
        int tx = threadIdx.x;
        if (tx < 32) {
            int c = tx & 15;
            const float* a = (tx < 16) ? al2 : ar2;
            float s = 0.f;
            for (int o = 0; o < C_OUT; o++) s += W2[c * C_OUT + o] * a[o];
            if (tx < 16) wl2[c] = s; else wr2[c] = s;
        }
        return;
    }
    if (blockIdx.x == 0) scan_one(cnt1, off1, cur1, N_DST1);
    else                 scan_one(cnt2, off2, cur2, N_DST2);
}

__global__ __launch_bounds__(256) void k_scatter(
    const int* __restrict__ s1, const int* __restrict__ d1, const float* __restrict__ w1,
    int* __restrict__ cur1, int2* __restrict__ sw1,
    const int* __restrict__ s2, const int* __restrict__ d2, const float* __restrict__ w2,
    int* __restrict__ cur2, int2* __restrict__ sw2)
{
    int e = blockIdx.x * 256 + threadIdx.x;
    if (e < E1) {
        int d = d1[e];
        int p = atomicAdd(&cur1[d], 1);
        sw1[p] = make_int2(s1[e], __float_as_int(w1[e]));
    } else if (e < E1 + E2) {
        int ee = e - E1;
        int d = d2[ee];
        int p = atomicAdd(&cur2[d], 1);
        sw2[p] = make_int2(s2[ee], __float_as_int(w2[ee]));
    }
}

// ---------------- fused GAT layer: ONE WAVE PER DST ---------------------
// lane = t*4 + q (t<12 active, lanes 48..63 idle). Each edge is loaded
// ONCE per wave (wave-uniform sw broadcast) and serves all 12 t-planes:
// 3x fewer vmem instructions than the 16-lane-per-(d,t) shape. No
// eslot reduction needed (each lane owns its (t,q) slice end-to-end).
// No max shift: logits bounded (~[-1,4] for this model), den >= ~6.
template <int NDST, int NSRC, bool FINAL>
__global__ __launch_bounds__(256) void k_gat(
    const int* __restrict__ off, const int2* __restrict__ sw,
    const float* __restrict__ el, const float* __restrict__ er,
    const float* __restrict__ hs, float* __restrict__ outp,
    const float* __restrict__ wl, const float* __restrict__ wr,
    float* __restrict__ el_out, float* __restrict__ er_out)
{
    __shared__ float w2s[FINAL ? HID * C_OUT : 1];
    int tx = threadIdx.x;
    if (FINAL) {
        for (int idx = tx; idx < HID * C_OUT; idx += 256) w2s[idx] = wl[idx];
        __syncthreads();
    }
    int wblk = xcd_swizzle(blockIdx.x, NDST / 4);
    int wave = tx >> 6;
    int lane = tx & 63;
    int t = lane >> 2;             // 0..15; active when t < 12
    int q = lane & 3;
    int d = wblk * 4 + wave;
    bool act = t < T;
    int tt = act ? t : 0;
    int start = off[d], end = off[d + 1];
    float erv = er[(size_t)tt * NDST + d];
    const float* elb = el + (size_t)tt * NSRC;
    const float* hsb = hs + (size_t)tt * NSRC * HID;

    float4 num = make_float4(0.f, 0.f, 0.f, 0.f);
    float den = 0.f;
    int i = start;
#define GEDGE(SA)                                                               \
        {                                                                       \
            float e_ = elb[SA.x];                                               \
            float4 h_ = *reinterpret_cast<const float4*>(hsb + (size_t)SA.x * HID + q * 4); \
            float ex_ = __expf(lrelu(e_ + erv, 0.2f));                          \
            den += ex_;                                                         \
            float c_ = ex_ * __int_as_float(SA.y);                              \
            num.x += c_ * h_.x; num.y += c_ * h_.y;                             \
            num.z += c_ * h_.z; num.w += c_ * h_.w;                             \
        }
    for (; i + 3 < end; i += 4) {   // 4 independent chains
        int2 sa = sw[i];
        int2 sb = sw[i + 1];
        int2 sc = sw[i + 2];
        int2 sd = sw[i + 3];
        float ea = elb[sa.x];
        float eb = elb[sb.x];
        float ec = elb[sc.x];
        float ed = elb[sd.x];
        float4 ha = *reinterpret_cast<const float4*>(hsb + (size_t)sa.x * HID + q * 4);
        float4 hb = *reinterpret_cast<const float4*>(hsb + (size_t)sb.x * HID + q * 4);
        float4 hc = *reinterpret_cast<const float4*>(hsb + (size_t)sc.x * HID + q * 4);
        float4 hd = *reinterpret_cast<const float4*>(hsb + (size_t)sd.x * HID + q * 4);
        float exa = __expf(lrelu(ea + erv, 0.2f));
        float exb = __expf(lrelu(eb + erv, 0.2f));
        float exc = __expf(lrelu(ec + erv, 0.2f));
        float exd = __expf(lrelu(ed + erv, 0.2f));
        den += (exa + exb) + (exc + exd);
        float ca = exa * __int_as_float(sa.y);
        float cb = exb * __int_as_float(sb.y);
        float cc = exc * __int_as_float(sc.y);
        float cd = exd * __int_as_float(sd.y);
        num.x += ca * ha.x + cb * hb.x + cc * hc.x + cd * hd.x;
        num.y += ca * ha.y + cb * hb.y + cc * hc.y + cd * hd.y;
        num.z += ca * ha.z + cb * hb.z + cc * hc.z + cd * hd.z;
        num.w += ca * ha.w + cb * hb.w + cc * hc.w + cd * hd.w;
    }
    for (; i + 1 < end; i += 2) {   // 2 independent chains
        int2 sa = sw[i];
        int2 sb = sw[i + 1];
        float ea = elb[sa.x];
        float eb = elb[sb.x];
        float4 ha = *reinterpret_cast<const float4*>(hsb + (size_t)sa.x * HID + q * 4);
        float4 hb = *reinterpret_cast<const float4*>(hsb + (size_t)sb.x * HID + q * 4);
        float exa = __expf(lrelu(ea + erv, 0.2f));
        float exb = __expf(lrelu(eb + erv, 0.2f));
        den += exa + exb;
        float ca = exa * __int_as_float(sa.y);
        float cb = exb * __int_as_float(sb.y);
        num.x += ca * ha.x + cb * hb.x;
        num.y += ca * ha.y + cb * hb.y;
        num.z += ca * ha.z + cb * hb.z;
        num.w += ca * ha.w + cb * hb.w;
    }
    if (i < end) {
        int2 sa = sw[i];
        GEDGE(sa);
    }
#undef GEDGE

    float inv = 1.f / (den + 1e-9f);
    float4 v = make_float4(num.x * inv, num.y * inv, num.z * inv, num.w * inv);

    if (!FINAL) {
        if (act) {
            v.x = lrelu(v.x, 0.01f); v.y = lrelu(v.y, 0.01f);
            v.z = lrelu(v.z, 0.01f); v.w = lrelu(v.w, 0.01f);
            int g = tt * NDST + d;
            *reinterpret_cast<float4*>(outp + (size_t)g * HID + q * 4) = v;
            float pl = v.x * wl[q * 4] + v.y * wl[q * 4 + 1] + v.z * wl[q * 4 + 2] + v.w * wl[q * 4 + 3];
            float pr = v.x * wr[q * 4] + v.y * wr[q * 4 + 1] + v.z * wr[q * 4 + 2] + v.w * wr[q * 4 + 3];
            pl += __shfl_xor(pl, 1); pl += __shfl_xor(pl, 2);
            pr += __shfl_xor(pr, 1); pr += __shfl_xor(pr, 2);
            if (q == 0) {
                el_out[g] = pl;
                if (d < N_DST2) er_out[(size_t)tt * N_DST2 + d] = pr;
            }
        }
    } else {
        if (act) {
            float4 v1, v2, v3;
            v1.x = __shfl_xor(v.x, 1); v1.y = __shfl_xor(v.y, 1); v1.z = __shfl_xor(v.z, 1); v1.w = __shfl_xor(v.w, 1);
            v2.x = __shfl_xor(v.x, 2); v2.y = __shfl_xor(v.y, 2); v2.z = __shfl_xor(v.z, 2); v2.w = __shfl_xor(v.w, 2);
            v3.x = __shfl_xor(v.x, 3); v3.y = __shfl_xor(v.y, 3); v3.z = __shfl_xor(v.z, 3); v3.w = __shfl_xor(v.w, 3);
            int obase = q * 8;
            float out8[8];
#pragma unroll
            for (int oo = 0; oo < 8; oo++) out8[oo] = 0.f;
#define ACCQ(Q, R0)                                                             \
            {                                                                   \
                int r0 = (R0) * 4;                                              \
                _Pragma("unroll")                                               \
                for (int oo = 0; oo < 8; oo++)                                  \
                    out8[oo] += (Q).x * w2s[(r0 + 0) * C_OUT + obase + oo]      \
                              + (Q).y * w2s[(r0 + 1) * C_OUT + obase + oo]      \
                              + (Q).z * w2s[(r0 + 2) * C_OUT + obase + oo]      \
                              + (Q).w * w2s[(r0 + 3) * C_OUT + obase + oo];     \
            }
            ACCQ(v,  q);
            ACCQ(v1, q ^ 1);
            ACCQ(v2, q ^ 2);
            ACCQ(v3, q ^ 3);
#undef ACCQ
            int g = tt * NDST + d;
            float* op = outp + (size_t)g * C_OUT + obase;
            float4 w0 = make_float4(lrelu(out8[0], 0.01f), lrelu(out8[1], 0.01f),
                                    lrelu(out8[2], 0.01f), lrelu(out8[3], 0.01f));
            float4 w1 = make_float4(lrelu(out8[4], 0.01f), lrelu(out8[5], 0.01f),
                                    lrelu(out8[6], 0.01f), lrelu(out8[7], 0.01f));
            *reinterpret_cast<float4*>(op) = w0;
            *reinterpret_cast<float4*>(op + 4) = w1;
        }
    }
}

extern "C" void kernel_launch(void* const* d_in, const int* in_sizes, int n_in,
                              void* d_out, int out_size, void* d_ws, size_t ws_size,
                              hipStream_t stream)
{
    const float* node_feat = (const float*)d_in[0];
    const int*   esrc1     = (const int*)d_in[1];
    const int*   edst1     = (const int*)d_in[2];
    const float* ew1       = (const float*)d_in[3];
    const int*   esrc2     = (const int*)d_in[4];
    const int*   edst2     = (const int*)d_in[5];
    const float* ew2       = (const float*)d_in[6];
    const float* W1        = (const float*)d_in[7];
    const float* a_l1      = (const float*)d_in[8];
    const float* a_r1      = (const float*)d_in[9];
    const float* W2        = (const float*)d_in[10];
    const float* a_l2      = (const float*)d_in[11];
    const float* a_r2      = (const float*)d_in[12];
    float* out = (float*)d_out;

    float* ws = (float*)d_ws;
    float* hs1 = ws;                        // 9,600,000  [T][N_SRC][16]
    float* el1 = hs1 + 9600000;             //   600,000  [T][N_SRC]
    float* er1 = el1 + 600000;              //   240,000  [T][N_DST1]
    float* h1  = er1 + 240000;              // 3,840,000  [T][N_DST1][16]
    float* el2 = h1 + 3840000;              //   240,000  [T][N_DST1]
    float* er2 = el2 + 240000;              //   120,000  [T][N_DST2]
    float* wl2 = er2 + 120000;              //        16
    float* wr2 = wl2 + 16;                  //        16
    int2* sw1 = (int2*)(wr2 + 16);          // E1 (16B-aligned)
    int2* sw2 = sw1 + E1;                   // E2
    int* cnt1 = (int*)(sw2 + E2);           //  20,000 (16B-aligned)
    int* cnt2 = cnt1 + N_DST1;              //  10,000
    int* off1 = cnt2 + N_DST2;              //  20,001
    int* cur1 = off1 + N_DST1 + 1;          //  20,000
    int* off2 = cur1 + N_DST1;              //  10,001
    int* cur2 = off2 + N_DST2 + 1;          //  10,000

    k_zero<<<30, 256, 0, stream>>>((int4*)cnt1, (N_DST1 + N_DST2) / 4);
    k_hist<<<(E1 + E2 + 255) / 256, 256, 0, stream>>>(edst1, edst2, cnt1, cnt2);
    k_scan<<<3, 1024, 0, stream>>>(cnt1, off1, cur1, cnt2, off2, cur2,
                                   W2, a_l2, a_r2, wl2, wr2);
    k_scatter<<<(E1 + E2 + 255) / 256, 256, 0, stream>>>(
        esrc1, edst1, ew1, cur1, sw1,
        esrc2, edst2, ew2, cur2, sw2);

    {
        dim3 g((N_SRC + 63) / 64, T);
        k_transform1<<<g, 256, 0, stream>>>(node_feat, W1, a_l1, a_r1, hs1, el1, er1);
    }
    k_gat<N_DST1, N_SRC, false><<<N_DST1 / 4, 256, 0, stream>>>(
        off1, sw1, el1, er1, hs1, h1, wl2, wr2, el2, er2);
    k_gat<N_DST2, N_DST1, true><<<N_DST2 / 4, 256, 0, stream>>>(
        off2, sw2, el2, er2, h1, out, W2, nullptr, nullptr, nullptr);
}

// Round 19
// 206.962 us; speedup vs baseline: 2.5634x; 1.2793x over previous
//
#include <hip/hip_runtime.h>
#include <hip/hip_fp16.h>

#define N_SRC 50000
#define N_DST1 20000
#define N_DST2 10000
#define E1 320000
#define E2 160000
#define T 12
#define C_IN 64
#define HID 16
#define C_OUT 32

struct H4 { __half2 a, b; };   // 8-byte packed half4

__device__ __forceinline__ float lrelu(float x, float s) { return x > 0.f ? x : s * x; }

// Bijective XCD-aware swizzle: XCD x = p%8 owns a contiguous logical chunk.
__device__ __forceinline__ int xcd_swizzle(int p, int W) {
    int x = p & 7, k = p >> 3;
    int q = W >> 3, r = W & 7;
    return (x < r ? x * (q + 1) : r * (q + 1) + (x - r) * q) + k;
}

// load one quarter-row of h: fp16 (layer 1) or fp32 (layer 2)
template <bool HALF>
__device__ __forceinline__ float4 load_h(const void* base, int s, int q) {
    if (HALF) {
        const __half* p = (const __half*)base + (size_t)s * HID + q * 4;
        H4 hv = *reinterpret_cast<const H4*>(p);
        float2 lo = __half22float2(hv.a);
        float2 hi = __half22float2(hv.b);
        return make_float4(lo.x, lo.y, hi.x, hi.y);
    } else {
        return *reinterpret_cast<const float4*>((const float*)base + (size_t)s * HID + q * 4);
    }
}

__global__ __launch_bounds__(256) void k_zero(int4* __restrict__ p, int n4)
{
    int i = blockIdx.x * 256 + threadIdx.x;
    if (i < n4) p[i] = make_int4(0, 0, 0, 0);
}

// ---------------- Layer-1 transform: 64-node tile; hs1 stored fp16 ------
__global__ __launch_bounds__(256) void k_transform1(
    const float* __restrict__ nf, const float* __restrict__ W1,
    const float* __restrict__ a_l, const float* __restrict__ a_r,
    __half* __restrict__ hs1, float* __restrict__ el1, float* __restrict__ er1)
{
    __shared__ float xs[64][68];
    __shared__ float w[C_IN][HID];
    __shared__ float al[HID], ar[HID];
    int tx = threadIdx.x;
    int t = blockIdx.y;
    int n0 = blockIdx.x * 64;
    int nrem = N_SRC - n0; if (nrem > 64) nrem = 64;

    reinterpret_cast<float4*>(&w[0][0])[tx] = reinterpret_cast<const float4*>(W1)[tx];
    if (tx < HID) al[tx] = a_l[tx];
    else if (tx < 2 * HID) ar[tx - HID] = a_r[tx - HID];

    const float4* gp = reinterpret_cast<const float4*>(nf + ((size_t)t * N_SRC + n0) * C_IN);
#pragma unroll
    for (int k = 0; k < 4; k++) {
        int f = k * 256 + tx;
        int node = f >> 4;
        if (node < nrem)
            *reinterpret_cast<float4*>(&xs[node][(f & 15) * 4]) = gp[f];
    }
    __syncthreads();

    int q = tx & 3;
    int nn = tx >> 2;
    float4 acc = make_float4(0.f, 0.f, 0.f, 0.f);
#pragma unroll
    for (int c4 = 0; c4 < 16; c4++) {
        float4 xA = *reinterpret_cast<const float4*>(&xs[nn][c4 * 4]);
        float4 w0 = *reinterpret_cast<const float4*>(&w[c4 * 4 + 0][q * 4]);
        float4 w1 = *reinterpret_cast<const float4*>(&w[c4 * 4 + 1][q * 4]);
        float4 w2 = *reinterpret_cast<const float4*>(&w[c4 * 4 + 2][q * 4]);
        float4 w3 = *reinterpret_cast<const float4*>(&w[c4 * 4 + 3][q * 4]);
        acc.x += xA.x * w0.x + xA.y * w1.x + xA.z * w2.x + xA.w * w3.x;
        acc.y += xA.x * w0.y + xA.y * w1.y + xA.z * w2.y + xA.w * w3.y;
        acc.z += xA.x * w0.z + xA.y * w1.z + xA.z * w2.z + xA.w * w3.z;
        acc.w += xA.x * w0.w + xA.y * w1.w + xA.z * w2.w + xA.w * w3.w;
    }

    float el = acc.x * al[q * 4] + acc.y * al[q * 4 + 1] + acc.z * al[q * 4 + 2] + acc.w * al[q * 4 + 3];
    float er = acc.x * ar[q * 4] + acc.y * ar[q * 4 + 1] + acc.z * ar[q * 4 + 2] + acc.w * ar[q * 4 + 3];
    el += __shfl_xor(el, 1); el += __shfl_xor(el, 2);
    er += __shfl_xor(er, 1); er += __shfl_xor(er, 2);

    if (nn < nrem) {
        __half* hb = hs1 + ((size_t)t * N_SRC + n0) * HID;
        H4 pk;
        pk.a = __floats2half2_rn(acc.x, acc.y);
        pk.b = __floats2half2_rn(acc.z, acc.w);
        *reinterpret_cast<H4*>(hb + (size_t)nn * HID + q * 4) = pk;
        if (q == 0) {
            int n = n0 + nn;
            el1[(size_t)t * N_SRC + n] = el;
            if (n < N_DST1) er1[(size_t)t * N_DST1 + n] = er;
        }
    }
}

// ---------------- CSR build: parallel hist + scan (+wvec) ---------------
__global__ __launch_bounds__(256) void k_hist(
    const int* __restrict__ d1, const int* __restrict__ d2,
    int* __restrict__ cnt1, int* __restrict__ cnt2)
{
    int e = blockIdx.x * 256 + threadIdx.x;
    if (e < E1) atomicAdd(&cnt1[d1[e]], 1);
    else if (e < E1 + E2) atomicAdd(&cnt2[d2[e - E1]], 1);
}

__device__ void scan_one(const int* cnt, int* off, int* cur, int N)
{
    __shared__ int part[1024];
    int tx = threadIdx.x;
    int CH = (N + 1023) / 1024;
    int base = tx * CH;
    int p = 0;
    for (int k = 0; k < CH; k++) { int i = base + k; if (i < N) p += cnt[i]; }
    part[tx] = p;
    __syncthreads();
#pragma unroll
    for (int d = 1; d < 1024; d <<= 1) {
        int v = (tx >= d) ? part[tx - d] : 0;
        __syncthreads();
        part[tx] += v;
        __syncthreads();
    }
    int run = (tx == 0) ? 0 : part[tx - 1];
    if (tx == 0) off[0] = 0;
    for (int k = 0; k < CH; k++) {
        int i = base + k;
        if (i < N) { cur[i] = run; run += cnt[i]; off[i + 1] = run; }
    }
}

__global__ __launch_bounds__(1024) void k_scan(
    const int* __restrict__ cnt1, int* __restrict__ off1, int* __restrict__ cur1,
    const int* __restrict__ cnt2, int* __restrict__ off2, int* __restrict__ cur2,
    const float* __restrict__ W2, const float* __restrict__ al2,
    const float* __restrict__ ar2, float* __restrict__ wl2, float* __restrict__ wr2)
{
    if (blockIdx.x == 2) {
        int tx = threadIdx.x;
        if (tx < 32) {
            int c = tx & 15;
            const float* a = (tx < 16) ? al2 : ar2;
            float s = 0.f;
            for (int o = 0; o < C_OUT; o++) s += W2[c * C_OUT + o] * a[o];
            if (tx < 16) wl2[c] = s; else wr2[c] = s;
        }
        return;
    }
    if (blockIdx.x == 0) scan_one(cnt1, off1, cur1, N_DST1);
    else                 scan_one(cnt2, off2, cur2, N_DST2);
}

__global__ __launch_bounds__(256) void k_scatter(
    const int* __restrict__ s1, const int* __restrict__ d1, const float* __restrict__ w1,
    int* __restrict__ cur1, int2* __restrict__ sw1,
    const int* __restrict__ s2, const int* __restrict__ d2, const float* __restrict__ w2,
    int* __restrict__ cur2, int2* __restrict__ sw2)
{
    int e = blockIdx.x * 256 + threadIdx.x;
    if (e < E1) {
        int d = d1[e];
        int p = atomicAdd(&cur1[d], 1);
        sw1[p] = make_int2(s1[e], __float_as_int(w1[e]));
    } else if (e < E1 + E2) {
        int ee = e - E1;
        int d = d2[ee];
        int p = atomicAdd(&cur2[d], 1);
        sw2[p] = make_int2(s2[ee], __float_as_int(w2[ee]));
    }
}

// ---------------- fused GAT layer: 16 lanes per (dst,t) -----------------
// lane16 = eslot*4 + q. 4/2/1 independent gather chains (r13 lever).
// HHS: hs stored fp16 (layer 1) vs fp32 (layer 2).
// No max shift: logits bounded (~[-1,4] for this model), den >= ~6.
template <int NDST, int NSRC, bool FINAL, bool HHS>
__global__ __launch_bounds__(256) void k_gat(
    const int* __restrict__ off, const int2* __restrict__ sw,
    const float* __restrict__ el, const float* __restrict__ er,
    const void* __restrict__ hs, float* __restrict__ outp,
    const float* __restrict__ wl, const float* __restrict__ wr,
    float* __restrict__ el_out, float* __restrict__ er_out)
{
    __shared__ float w2s[FINAL ? HID * C_OUT : 1];
    int tx = threadIdx.x;
    if (FINAL) {
        for (int idx = tx; idx < HID * C_OUT; idx += 256) w2s[idx] = wl[idx];
        __syncthreads();
    }
    int wblk = xcd_swizzle(blockIdx.x, (NDST * T) / 16);
    int grp = tx >> 4;
    int lane16 = tx & 15;
    int q = lane16 & 3;
    int eslot = lane16 >> 2;
    int g = wblk * 16 + grp;       // t*NDST + d
    int t = g / NDST;
    int d = g - t * NDST;
    int start = off[d], end = off[d + 1];
    float erv = er[g];
    const float* elb = el + (size_t)t * NSRC;
    const void* hsb = HHS
        ? (const void*)((const __half*)hs + (size_t)t * NSRC * HID)
        : (const void*)((const float*)hs + (size_t)t * NSRC * HID);

    float4 num = make_float4(0.f, 0.f, 0.f, 0.f);
    float den = 0.f;
    int i = start + eslot;
    for (; i + 12 < end; i += 16) {   // 4 independent chains
        int2 sa = sw[i];
        int2 sb = sw[i + 4];
        int2 sc = sw[i + 8];
        int2 sd = sw[i + 12];
        float ea = elb[sa.x];
        float eb = elb[sb.x];
        float ec = elb[sc.x];
        float ed = elb[sd.x];
        float4 ha = load_h<HHS>(hsb, sa.x, q);
        float4 hb = load_h<HHS>(hsb, sb.x, q);
        float4 hc = load_h<HHS>(hsb, sc.x, q);
        float4 hd = load_h<HHS>(hsb, sd.x, q);
        float exa = __expf(lrelu(ea + erv, 0.2f));
        float exb = __expf(lrelu(eb + erv, 0.2f));
        float exc = __expf(lrelu(ec + erv, 0.2f));
        float exd = __expf(lrelu(ed + erv, 0.2f));
        den += (exa + exb) + (exc + exd);
        float ca = exa * __int_as_float(sa.y);
        float cb = exb * __int_as_float(sb.y);
        float cc = exc * __int_as_float(sc.y);
        float cd = exd * __int_as_float(sd.y);
        num.x += ca * ha.x + cb * hb.x + cc * hc.x + cd * hd.x;
        num.y += ca * ha.y + cb * hb.y + cc * hc.y + cd * hd.y;
        num.z += ca * ha.z + cb * hb.z + cc * hc.z + cd * hd.z;
        num.w += ca * ha.w + cb * hb.w + cc * hc.w + cd * hd.w;
    }
    for (; i + 4 < end; i += 8) {     // 2 independent chains
        int2 sa = sw[i];
        int2 sb = sw[i + 4];
        float ea = elb[sa.x];
        float eb = elb[sb.x];
        float4 ha = load_h<HHS>(hsb, sa.x, q);
        float4 hb = load_h<HHS>(hsb, sb.x, q);
        float exa = __expf(lrelu(ea + erv, 0.2f));
        float exb = __expf(lrelu(eb + erv, 0.2f));
        den += exa + exb;
        float ca = exa * __int_as_float(sa.y);
        float cb = exb * __int_as_float(sb.y);
        num.x += ca * ha.x + cb * hb.x;
        num.y += ca * ha.y + cb * hb.y;
        num.z += ca * ha.z + cb * hb.z;
        num.w += ca * ha.w + cb * hb.w;
    }
    if (i < end) {
        int2 sa = sw[i];
        float ea = elb[sa.x];
        float4 ha = load_h<HHS>(hsb, sa.x, q);
        float exa = __expf(lrelu(ea + erv, 0.2f));
        den += exa;
        float ca = exa * __int_as_float(sa.y);
        num.x += ca * ha.x; num.y += ca * ha.y;
        num.z += ca * ha.z; num.w += ca * ha.w;
    }
#pragma unroll
    for (int mk = 4; mk <= 8; mk <<= 1) {
        num.x += __shfl_xor(num.x, mk);
        num.y += __shfl_xor(num.y, mk);
        num.z += __shfl_xor(num.z, mk);
        num.w += __shfl_xor(num.w, mk);
        den   += __shfl_xor(den, mk);
    }
    float inv = 1.f / (den + 1e-9f);
    float4 v = make_float4(num.x * inv, num.y * inv, num.z * inv, num.w * inv);

    if (!FINAL) {
        v.x = lrelu(v.x, 0.01f); v.y = lrelu(v.y, 0.01f);
        v.z = lrelu(v.z, 0.01f); v.w = lrelu(v.w, 0.01f);
        if (eslot == 0) {
            *reinterpret_cast<float4*>(outp + (size_t)g * HID + q * 4) = v;
            float pl = v.x * wl[q * 4] + v.y * wl[q * 4 + 1] + v.z * wl[q * 4 + 2] + v.w * wl[q * 4 + 3];
            float pr = v.x * wr[q * 4] + v.y * wr[q * 4 + 1] + v.z * wr[q * 4 + 2] + v.w * wr[q * 4 + 3];
            pl += __shfl_xor(pl, 1); pl += __shfl_xor(pl, 2);
            pr += __shfl_xor(pr, 1); pr += __shfl_xor(pr, 2);
            if (q == 0) {
                el_out[g] = pl;
                if (d < N_DST2) er_out[(size_t)t * N_DST2 + d] = pr;
            }
        }
    } else {
        float4 v1, v2, v3;
        v1.x = __shfl_xor(v.x, 1); v1.y = __shfl_xor(v.y, 1); v1.z = __shfl_xor(v.z, 1); v1.w = __shfl_xor(v.w, 1);
        v2.x = __shfl_xor(v.x, 2); v2.y = __shfl_xor(v.y, 2); v2.z = __shfl_xor(v.z, 2); v2.w = __shfl_xor(v.w, 2);
        v3.x = __shfl_xor(v.x, 3); v3.y = __shfl_xor(v.y, 3); v3.z = __shfl_xor(v.z, 3); v3.w = __shfl_xor(v.w, 3);
        int obase = q * 8;
        float out8[8];
#pragma unroll
        for (int oo = 0; oo < 8; oo++) out8[oo] = 0.f;
#define ACCQ(Q, R0)                                                             \
        {                                                                       \
            int r0 = (R0) * 4;                                                  \
            _Pragma("unroll")                                                   \
            for (int oo = 0; oo < 8; oo++)                                      \
                out8[oo] += (Q).x * w2s[(r0 + 0) * C_OUT + obase + oo]          \
                          + (Q).y * w2s[(r0 + 1) * C_OUT + obase + oo]          \
                          + (Q).z * w2s[(r0 + 2) * C_OUT + obase + oo]          \
                          + (Q).w * w2s[(r0 + 3) * C_OUT + obase + oo];         \
        }
        ACCQ(v,  q);
        ACCQ(v1, q ^ 1);
        ACCQ(v2, q ^ 2);
        ACCQ(v3, q ^ 3);
#undef ACCQ
        if (eslot == 0) {
            float* op = outp + (size_t)g * C_OUT + obase;
            float4 w0 = make_float4(lrelu(out8[0], 0.01f), lrelu(out8[1], 0.01f),
                                    lrelu(out8[2], 0.01f), lrelu(out8[3], 0.01f));
            float4 w1 = make_float4(lrelu(out8[4], 0.01f), lrelu(out8[5], 0.01f),
                                    lrelu(out8[6], 0.01f), lrelu(out8[7], 0.01f));
            *reinterpret_cast<float4*>(op) = w0;
            *reinterpret_cast<float4*>(op + 4) = w1;
        }
    }
}

extern "C" void kernel_launch(void* const* d_in, const int* in_sizes, int n_in,
                              void* d_out, int out_size, void* d_ws, size_t ws_size,
                              hipStream_t stream)
{
    const float* node_feat = (const float*)d_in[0];
    const int*   esrc1     = (const int*)d_in[1];
    const int*   edst1     = (const int*)d_in[2];
    const float* ew1       = (const float*)d_in[3];
    const int*   esrc2     = (const int*)d_in[4];
    const int*   edst2     = (const int*)d_in[5];
    const float* ew2       = (const float*)d_in[6];
    const float* W1        = (const float*)d_in[7];
    const float* a_l1      = (const float*)d_in[8];
    const float* a_r1      = (const float*)d_in[9];
    const float* W2        = (const float*)d_in[10];
    const float* a_l2      = (const float*)d_in[11];
    const float* a_r2      = (const float*)d_in[12];
    float* out = (float*)d_out;

    float* ws = (float*)d_ws;
    __half* hs1 = (__half*)ws;              // 9,600,000 halfs = 19.2MB
    float* el1 = ws + 4800000;              //   600,000  [T][N_SRC]
    float* er1 = el1 + 600000;              //   240,000  [T][N_DST1]
    float* h1  = er1 + 240000;              // 3,840,000  [T][N_DST1][16] fp32
    float* el2 = h1 + 3840000;              //   240,000  [T][N_DST1]
    float* er2 = el2 + 240000;              //   120,000  [T][N_DST2]
    float* wl2 = er2 + 120000;              //        16
    float* wr2 = wl2 + 16;                  //        16
    int2* sw1 = (int2*)(wr2 + 16);          // E1 (16B-aligned)
    int2* sw2 = sw1 + E1;                   // E2
    int* cnt1 = (int*)(sw2 + E2);           //  20,000 (16B-aligned)
    int* cnt2 = cnt1 + N_DST1;              //  10,000
    int* off1 = cnt2 + N_DST2;              //  20,001
    int* cur1 = off1 + N_DST1 + 1;          //  20,000
    int* off2 = cur1 + N_DST1;              //  10,001
    int* cur2 = off2 + N_DST2 + 1;          //  10,000

    k_zero<<<30, 256, 0, stream>>>((int4*)cnt1, (N_DST1 + N_DST2) / 4);
    k_hist<<<(E1 + E2 + 255) / 256, 256, 0, stream>>>(edst1, edst2, cnt1, cnt2);
    k_scan<<<3, 1024, 0, stream>>>(cnt1, off1, cur1, cnt2, off2, cur2,
                                   W2, a_l2, a_r2, wl2, wr2);
    k_scatter<<<(E1 + E2 + 255) / 256, 256, 0, stream>>>(
        esrc1, edst1, ew1, cur1, sw1,
        esrc2, edst2, ew2, cur2, sw2);

    {
        dim3 g((N_SRC + 63) / 64, T);
        k_transform1<<<g, 256, 0, stream>>>(node_feat, W1, a_l1, a_r1, hs1, el1, er1);
    }
    k_gat<N_DST1, N_SRC, false, true><<<(N_DST1 * T) / 16, 256, 0, stream>>>(
        off1, sw1, el1, er1, hs1, h1, wl2, wr2, el2, er2);
    k_gat<N_DST2, N_DST1, true, false><<<(N_DST2 * T) / 16, 256, 0, stream>>>(
        off2, sw2, el2, er2, h1, out, W2, nullptr, nullptr, nullptr);
}

// Round 20
// 203.131 us; speedup vs baseline: 2.6117x; 1.0189x over previous
//
#include <hip/hip_runtime.h>
#include <hip/hip_fp16.h>

#define N_SRC 50000
#define N_DST1 20000
#define N_DST2 10000
#define E1 320000
#define E2 160000
#define T 12
#define C_IN 64
#define HID 16
#define C_OUT 32
#define RW 20   // packed row stride in halfs: 16 fp16 h + fp32 el + pad = 40B

struct H4 { __half2 a, b; };   // 8-byte packed half4

__device__ __forceinline__ float lrelu(float x, float s) { return x > 0.f ? x : s * x; }

// Bijective XCD-aware swizzle: XCD x = p%8 owns a contiguous logical chunk.
__device__ __forceinline__ int xcd_swizzle(int p, int W) {
    int x = p & 7, k = p >> 3;
    int q = W >> 3, r = W & 7;
    return (x < r ? x * (q + 1) : r * (q + 1) + (x - r) * q) + k;
}

// load (el, h-quarter) for one edge.
// PACKED: both from one 40B row (el shares the row's cache line).
template <bool PACKED>
__device__ __forceinline__ void edge_load(const void* hsb, const float* elb,
                                          int s, int q, float& e_out, float4& h_out)
{
    if (PACKED) {
        const __half* r = (const __half*)hsb + (size_t)s * RW;
        e_out = *reinterpret_cast<const float*>(r + 16);
        H4 hv = *reinterpret_cast<const H4*>(r + q * 4);
        float2 lo = __half22float2(hv.a);
        float2 hi = __half22float2(hv.b);
        h_out = make_float4(lo.x, lo.y, hi.x, hi.y);
    } else {
        e_out = elb[s];
        h_out = *reinterpret_cast<const float4*>((const float*)hsb + (size_t)s * HID + q * 4);
    }
}

__global__ __launch_bounds__(256) void k_zero(int4* __restrict__ p, int n4)
{
    int i = blockIdx.x * 256 + threadIdx.x;
    if (i < n4) p[i] = make_int4(0, 0, 0, 0);
}

// ---------------- Layer-1 transform: 64-node tile; packed 40B rows ------
__global__ __launch_bounds__(256) void k_transform1(
    const float* __restrict__ nf, const float* __restrict__ W1,
    const float* __restrict__ a_l, const float* __restrict__ a_r,
    __half* __restrict__ hs1x, float* __restrict__ er1)
{
    __shared__ float xs[64][68];
    __shared__ float w[C_IN][HID];
    __shared__ float al[HID], ar[HID];
    int tx = threadIdx.x;
    int t = blockIdx.y;
    int n0 = blockIdx.x * 64;
    int nrem = N_SRC - n0; if (nrem > 64) nrem = 64;

    reinterpret_cast<float4*>(&w[0][0])[tx] = reinterpret_cast<const float4*>(W1)[tx];
    if (tx < HID) al[tx] = a_l[tx];
    else if (tx < 2 * HID) ar[tx - HID] = a_r[tx - HID];

    const float4* gp = reinterpret_cast<const float4*>(nf + ((size_t)t * N_SRC + n0) * C_IN);
#pragma unroll
    for (int k = 0; k < 4; k++) {
        int f = k * 256 + tx;
        int node = f >> 4;
        if (node < nrem)
            *reinterpret_cast<float4*>(&xs[node][(f & 15) * 4]) = gp[f];
    }
    __syncthreads();

    int q = tx & 3;
    int nn = tx >> 2;
    float4 acc = make_float4(0.f, 0.f, 0.f, 0.f);
#pragma unroll
    for (int c4 = 0; c4 < 16; c4++) {
        float4 xA = *reinterpret_cast<const float4*>(&xs[nn][c4 * 4]);
        float4 w0 = *reinterpret_cast<const float4*>(&w[c4 * 4 + 0][q * 4]);
        float4 w1 = *reinterpret_cast<const float4*>(&w[c4 * 4 + 1][q * 4]);
        float4 w2 = *reinterpret_cast<const float4*>(&w[c4 * 4 + 2][q * 4]);
        float4 w3 = *reinterpret_cast<const float4*>(&w[c4 * 4 + 3][q * 4]);
        acc.x += xA.x * w0.x + xA.y * w1.x + xA.z * w2.x + xA.w * w3.x;
        acc.y += xA.x * w0.y + xA.y * w1.y + xA.z * w2.y + xA.w * w3.y;
        acc.z += xA.x * w0.z + xA.y * w1.z + xA.z * w2.z + xA.w * w3.z;
        acc.w += xA.x * w0.w + xA.y * w1.w + xA.z * w2.w + xA.w * w3.w;
    }

    float el = acc.x * al[q * 4] + acc.y * al[q * 4 + 1] + acc.z * al[q * 4 + 2] + acc.w * al[q * 4 + 3];
    float er = acc.x * ar[q * 4] + acc.y * ar[q * 4 + 1] + acc.z * ar[q * 4 + 2] + acc.w * ar[q * 4 + 3];
    el += __shfl_xor(el, 1); el += __shfl_xor(el, 2);
    er += __shfl_xor(er, 1); er += __shfl_xor(er, 2);

    if (nn < nrem) {
        __half* hb = hs1x + ((size_t)t * N_SRC + n0) * RW;
        H4 pk;
        pk.a = __floats2half2_rn(acc.x, acc.y);
        pk.b = __floats2half2_rn(acc.z, acc.w);
        *reinterpret_cast<H4*>(hb + (size_t)nn * RW + q * 4) = pk;
        if (q == 0) {
            *reinterpret_cast<float*>(hb + (size_t)nn * RW + 16) = el;
            int n = n0 + nn;
            if (n < N_DST1) er1[(size_t)t * N_DST1 + n] = er;
        }
    }
}

// ---------------- CSR build: parallel hist + scan (+wvec) ---------------
__global__ __launch_bounds__(256) void k_hist(
    const int* __restrict__ d1, const int* __restrict__ d2,
    int* __restrict__ cnt1, int* __restrict__ cnt2)
{
    int e = blockIdx.x * 256 + threadIdx.x;
    if (e < E1) atomicAdd(&cnt1[d1[e]], 1);
    else if (e < E1 + E2) atomicAdd(&cnt2[d2[e - E1]], 1);
}

__device__ void scan_one(const int* cnt, int* off, int* cur, int N)
{
    __shared__ int part[1024];
    int tx = threadIdx.x;
    int CH = (N + 1023) / 1024;
    int base = tx * CH;
    int p = 0;
    for (int k = 0; k < CH; k++) { int i = base + k; if (i < N) p += cnt[i]; }
    part[tx] = p;
    __syncthreads();
#pragma unroll
    for (int d = 1; d < 1024; d <<= 1) {
        int v = (tx >= d) ? part[tx - d] : 0;
        __syncthreads();
        part[tx] += v;
        __syncthreads();
    }
    int run = (tx == 0) ? 0 : part[tx - 1];
    if (tx == 0) off[0] = 0;
    for (int k = 0; k < CH; k++) {
        int i = base + k;
        if (i < N) { cur[i] = run; run += cnt[i]; off[i + 1] = run; }
    }
}

__global__ __launch_bounds__(1024) void k_scan(
    const int* __restrict__ cnt1, int* __restrict__ off1, int* __restrict__ cur1,
    const int* __restrict__ cnt2, int* __restrict__ off2, int* __restrict__ cur2,
    const float* __restrict__ W2, const float* __restrict__ al2,
    const float* __restrict__ ar2, float* __restrict__ wl2, float* __restrict__ wr2)
{
    if (blockIdx.x == 2) {
        int tx = threadIdx.x;
        if (tx < 32) {
            int c = tx & 15;
            const float* a = (tx < 16) ? al2 : ar2;
            float s = 0.f;
            for (int o = 0; o < C_OUT; o++) s += W2[c * C_OUT + o] * a[o];
            if (tx < 16) wl2[c] = s; else wr2[c] = s;
        }
        return;
    }
    if (blockIdx.x == 0) scan_one(cnt1, off1, cur1, N_DST1);
    else                 scan_one(cnt2, off2, cur2, N_DST2);
}

__global__ __launch_bounds__(256) void k_scatter(
    const int* __restrict__ s1, const int* __restrict__ d1, const float* __restrict__ w1,
    int* __restrict__ cur1, int2* __restrict__ sw1,
    const int* __restrict__ s2, const int* __restrict__ d2, const float* __restrict__ w2,
    int* __restrict__ cur2, int2* __restrict__ sw2)
{
    int e = blockIdx.x * 256 + threadIdx.x;
    if (e < E1) {
        int d = d1[e];
        int p = atomicAdd(&cur1[d], 1);
        sw1[p] = make_int2(s1[e], __float_as_int(w1[e]));
    } else if (e < E1 + E2) {
        int ee = e - E1;
        int d = d2[ee];
        int p = atomicAdd(&cur2[d], 1);
        sw2[p] = make_int2(s2[ee], __float_as_int(w2[ee]));
    }
}

// ---------------- fused GAT layer: 16 lanes per (dst,t) -----------------
// lane16 = eslot*4 + q. 4/2/1 independent gather chains.
// PACKED (layer 1): el lives in the h-row -> ~1.5 lines/edge vs 2.
// No max shift: logits bounded (~[-1,4] for this model), den >= ~6.
template <int NDST, int NSRC, bool FINAL, bool PACKED>
__global__ __launch_bounds__(256) void k_gat(
    const int* __restrict__ off, const int2* __restrict__ sw,
    const float* __restrict__ el, const float* __restrict__ er,
    const void* __restrict__ hs, float* __restrict__ outp,
    const float* __restrict__ wl, const float* __restrict__ wr,
    float* __restrict__ el_out, float* __restrict__ er_out)
{
    __shared__ float w2s[FINAL ? HID * C_OUT : 1];
    int tx = threadIdx.x;
    if (FINAL) {
        for (int idx = tx; idx < HID * C_OUT; idx += 256) w2s[idx] = wl[idx];
        __syncthreads();
    }
    int wblk = xcd_swizzle(blockIdx.x, (NDST * T) / 16);
    int grp = tx >> 4;
    int lane16 = tx & 15;
    int q = lane16 & 3;
    int eslot = lane16 >> 2;
    int g = wblk * 16 + grp;       // t*NDST + d
    int t = g / NDST;
    int d = g - t * NDST;
    int start = off[d], end = off[d + 1];
    float erv = er[g];
    const float* elb = PACKED ? nullptr : (el + (size_t)t * NSRC);
    const void* hsb = PACKED
        ? (const void*)((const __half*)hs + (size_t)t * NSRC * RW)
        : (const void*)((const float*)hs + (size_t)t * NSRC * HID);

    float4 num = make_float4(0.f, 0.f, 0.f, 0.f);
    float den = 0.f;
    int i = start + eslot;
    for (; i + 12 < end; i += 16) {   // 4 independent chains
        int2 sa = sw[i];
        int2 sb = sw[i + 4];
        int2 sc = sw[i + 8];
        int2 sd = sw[i + 12];
        float ea, eb, ec, ed;
        float4 ha, hb, hc, hd;
        edge_load<PACKED>(hsb, elb, sa.x, q, ea, ha);
        edge_load<PACKED>(hsb, elb, sb.x, q, eb, hb);
        edge_load<PACKED>(hsb, elb, sc.x, q, ec, hc);
        edge_load<PACKED>(hsb, elb, sd.x, q, ed, hd);
        float exa = __expf(lrelu(ea + erv, 0.2f));
        float exb = __expf(lrelu(eb + erv, 0.2f));
        float exc = __expf(lrelu(ec + erv, 0.2f));
        float exd = __expf(lrelu(ed + erv, 0.2f));
        den += (exa + exb) + (exc + exd);
        float ca = exa * __int_as_float(sa.y);
        float cb = exb * __int_as_float(sb.y);
        float cc = exc * __int_as_float(sc.y);
        float cd = exd * __int_as_float(sd.y);
        num.x += ca * ha.x + cb * hb.x + cc * hc.x + cd * hd.x;
        num.y += ca * ha.y + cb * hb.y + cc * hc.y + cd * hd.y;
        num.z += ca * ha.z + cb * hb.z + cc * hc.z + cd * hd.z;
        num.w += ca * ha.w + cb * hb.w + cc * hc.w + cd * hd.w;
    }
    for (; i + 4 < end; i += 8) {     // 2 independent chains
        int2 sa = sw[i];
        int2 sb = sw[i + 4];
        float ea, eb;
        float4 ha, hb;
        edge_load<PACKED>(hsb, elb, sa.x, q, ea, ha);
        edge_load<PACKED>(hsb, elb, sb.x, q, eb, hb);
        float exa = __expf(lrelu(ea + erv, 0.2f));
        float exb = __expf(lrelu(eb + erv, 0.2f));
        den += exa + exb;
        float ca = exa * __int_as_float(sa.y);
        float cb = exb * __int_as_float(sb.y);
        num.x += ca * ha.x + cb * hb.x;
        num.y += ca * ha.y + cb * hb.y;
        num.z += ca * ha.z + cb * hb.z;
        num.w += ca * ha.w + cb * hb.w;
    }
    if (i < end) {
        int2 sa = sw[i];
        float ea;
        float4 ha;
        edge_load<PACKED>(hsb, elb, sa.x, q, ea, ha);
        float exa = __expf(lrelu(ea + erv, 0.2f));
        den += exa;
        float ca = exa * __int_as_float(sa.y);
        num.x += ca * ha.x; num.y += ca * ha.y;
        num.z += ca * ha.z; num.w += ca * ha.w;
    }
#pragma unroll
    for (int mk = 4; mk <= 8; mk <<= 1) {
        num.x += __shfl_xor(num.x, mk);
        num.y += __shfl_xor(num.y, mk);
        num.z += __shfl_xor(num.z, mk);
        num.w += __shfl_xor(num.w, mk);
        den   += __shfl_xor(den, mk);
    }
    float inv = 1.f / (den + 1e-9f);
    float4 v = make_float4(num.x * inv, num.y * inv, num.z * inv, num.w * inv);

    if (!FINAL) {
        v.x = lrelu(v.x, 0.01f); v.y = lrelu(v.y, 0.01f);
        v.z = lrelu(v.z, 0.01f); v.w = lrelu(v.w, 0.01f);
        if (eslot == 0) {
            *reinterpret_cast<float4*>(outp + (size_t)g * HID + q * 4) = v;
            float pl = v.x * wl[q * 4] + v.y * wl[q * 4 + 1] + v.z * wl[q * 4 + 2] + v.w * wl[q * 4 + 3];
            float pr = v.x * wr[q * 4] + v.y * wr[q * 4 + 1] + v.z * wr[q * 4 + 2] + v.w * wr[q * 4 + 3];
            pl += __shfl_xor(pl, 1); pl += __shfl_xor(pl, 2);
            pr += __shfl_xor(pr, 1); pr += __shfl_xor(pr, 2);
            if (q == 0) {
                el_out[g] = pl;
                if (d < N_DST2) er_out[(size_t)t * N_DST2 + d] = pr;
            }
        }
    } else {
        float4 v1, v2, v3;
        v1.x = __shfl_xor(v.x, 1); v1.y = __shfl_xor(v.y, 1); v1.z = __shfl_xor(v.z, 1); v1.w = __shfl_xor(v.w, 1);
        v2.x = __shfl_xor(v.x, 2); v2.y = __shfl_xor(v.y, 2); v2.z = __shfl_xor(v.z, 2); v2.w = __shfl_xor(v.w, 2);
        v3.x = __shfl_xor(v.x, 3); v3.y = __shfl_xor(v.y, 3); v3.z = __shfl_xor(v.z, 3); v3.w = __shfl_xor(v.w, 3);
        int obase = q * 8;
        float out8[8];
#pragma unroll
        for (int oo = 0; oo < 8; oo++) out8[oo] = 0.f;
#define ACCQ(Q, R0)                                                             \
        {                                                                       \
            int r0 = (R0) * 4;                                                  \
            _Pragma("unroll")                                                   \
            for (int oo = 0; oo < 8; oo++)                                      \
                out8[oo] += (Q).x * w2s[(r0 + 0) * C_OUT + obase + oo]          \
                          + (Q).y * w2s[(r0 + 1) * C_OUT + obase + oo]          \
                          + (Q).z * w2s[(r0 + 2) * C_OUT + obase + oo]          \
                          + (Q).w * w2s[(r0 + 3) * C_OUT + obase + oo];         \
        }
        ACCQ(v,  q);
        ACCQ(v1, q ^ 1);
        ACCQ(v2, q ^ 2);
        ACCQ(v3, q ^ 3);
#undef ACCQ
        if (eslot == 0) {
            float* op = outp + (size_t)g * C_OUT + obase;
            float4 w0 = make_float4(lrelu(out8[0], 0.01f), lrelu(out8[1], 0.01f),
                                    lrelu(out8[2], 0.01f), lrelu(out8[3], 0.01f));
            float4 w1 = make_float4(lrelu(out8[4], 0.01f), lrelu(out8[5], 0.01f),
                                    lrelu(out8[6], 0.01f), lrelu(out8[7], 0.01f));
            *reinterpret_cast<float4*>(op) = w0;
            *reinterpret_cast<float4*>(op + 4) = w1;
        }
    }
}

extern "C" void kernel_launch(void* const* d_in, const int* in_sizes, int n_in,
                              void* d_out, int out_size, void* d_ws, size_t ws_size,
                              hipStream_t stream)
{
    const float* node_feat = (const float*)d_in[0];
    const int*   esrc1     = (const int*)d_in[1];
    const int*   edst1     = (const int*)d_in[2];
    const float* ew1       = (const float*)d_in[3];
    const int*   esrc2     = (const int*)d_in[4];
    const int*   edst2     = (const int*)d_in[5];
    const float* ew2       = (const float*)d_in[6];
    const float* W1        = (const float*)d_in[7];
    const float* a_l1      = (const float*)d_in[8];
    const float* a_r1      = (const float*)d_in[9];
    const float* W2        = (const float*)d_in[10];
    const float* a_l2      = (const float*)d_in[11];
    const float* a_r2      = (const float*)d_in[12];
    float* out = (float*)d_out;

    float* ws = (float*)d_ws;
    __half* hs1x = (__half*)ws;             // 12,000,000 halfs = 24MB (packed rows)
    float* er1 = ws + 6000000;              //   240,000  [T][N_DST1]
    float* h1  = er1 + 240000;              // 3,840,000  [T][N_DST1][16] fp32
    float* el2 = h1 + 3840000;              //   240,000  [T][N_DST1]
    float* er2 = el2 + 240000;              //   120,000  [T][N_DST2]
    float* wl2 = er2 + 120000;              //        16
    float* wr2 = wl2 + 16;                  //        16
    int2* sw1 = (int2*)(wr2 + 16);          // E1 (16B-aligned)
    int2* sw2 = sw1 + E1;                   // E2
    int* cnt1 = (int*)(sw2 + E2);           //  20,000 (16B-aligned)
    int* cnt2 = cnt1 + N_DST1;              //  10,000
    int* off1 = cnt2 + N_DST2;              //  20,001
    int* cur1 = off1 + N_DST1 + 1;          //  20,000
    int* off2 = cur1 + N_DST1;              //  10,001
    int* cur2 = off2 + N_DST2 + 1;          //  10,000

    k_zero<<<30, 256, 0, stream>>>((int4*)cnt1, (N_DST1 + N_DST2) / 4);
    k_hist<<<(E1 + E2 + 255) / 256, 256, 0, stream>>>(edst1, edst2, cnt1, cnt2);
    k_scan<<<3, 1024, 0, stream>>>(cnt1, off1, cur1, cnt2, off2, cur2,
                                   W2, a_l2, a_r2, wl2, wr2);
    k_scatter<<<(E1 + E2 + 255) / 256, 256, 0, stream>>>(
        esrc1, edst1, ew1, cur1, sw1,
        esrc2, edst2, ew2, cur2, sw2);

    {
        dim3 g((N_SRC + 63) / 64, T);
        k_transform1<<<g, 256, 0, stream>>>(node_feat, W1, a_l1, a_r1, hs1x, er1);
    }
    k_gat<N_DST1, N_SRC, false, true><<<(N_DST1 * T) / 16, 256, 0, stream>>>(
        off1, sw1, nullptr, er1, hs1x, h1, wl2, wr2, el2, er2);
    k_gat<N_DST2, N_DST1, true, false><<<(N_DST2 * T) / 16, 256, 0, stream>>>(
        off2, sw2, el2, er2, h1, out, W2, nullptr, nullptr, nullptr);
}

// Round 21
// 200.875 us; speedup vs baseline: 2.6410x; 1.0112x over previous
//
#include <hip/hip_runtime.h>
#include <hip/hip_fp16.h>

#define N_SRC 50000
#define N_DST1 20000
#define N_DST2 10000
#define E1 320000
#define E2 160000
#define T 12
#define C_IN 64
#define HID 16
#define C_OUT 32
#define RW 20   // packed row stride in halfs: 16 fp16 h + fp32 el + pad = 40B

struct H4 { __half2 a, b; };   // 8-byte packed half4

__device__ __forceinline__ float lrelu(float x, float s) { return x > 0.f ? x : s * x; }

// Bijective XCD-aware swizzle: XCD x = p%8 owns a contiguous logical chunk.
__device__ __forceinline__ int xcd_swizzle(int p, int W) {
    int x = p & 7, k = p >> 3;
    int q = W >> 3, r = W & 7;
    return (x < r ? x * (q + 1) : r * (q + 1) + (x - r) * q) + k;
}

// load (el, h-quarter) for one edge from a packed 40B row.
__device__ __forceinline__ void edge_load(const __half* hsb, int s, int q,
                                          float& e_out, float4& h_out)
{
    const __half* r = hsb + (size_t)s * RW;
    e_out = *reinterpret_cast<const float*>(r + 16);
    H4 hv = *reinterpret_cast<const H4*>(r + q * 4);
    float2 lo = __half22float2(hv.a);
    float2 hi = __half22float2(hv.b);
    h_out = make_float4(lo.x, lo.y, hi.x, hi.y);
}

__global__ __launch_bounds__(256) void k_zero(int4* __restrict__ p, int n4)
{
    int i = blockIdx.x * 256 + threadIdx.x;
    if (i < n4) p[i] = make_int4(0, 0, 0, 0);
}

// ---------------- Layer-1 transform: 64-node tile; packed 40B rows ------
__global__ __launch_bounds__(256) void k_transform1(
    const float* __restrict__ nf, const float* __restrict__ W1,
    const float* __restrict__ a_l, const float* __restrict__ a_r,
    __half* __restrict__ hs1x, float* __restrict__ er1)
{
    __shared__ float xs[64][68];
    __shared__ float w[C_IN][HID];
    __shared__ float al[HID], ar[HID];
    int tx = threadIdx.x;
    int t = blockIdx.y;
    int n0 = blockIdx.x * 64;
    int nrem = N_SRC - n0; if (nrem > 64) nrem = 64;

    reinterpret_cast<float4*>(&w[0][0])[tx] = reinterpret_cast<const float4*>(W1)[tx];
    if (tx < HID) al[tx] = a_l[tx];
    else if (tx < 2 * HID) ar[tx - HID] = a_r[tx - HID];

    const float4* gp = reinterpret_cast<const float4*>(nf + ((size_t)t * N_SRC + n0) * C_IN);
#pragma unroll
    for (int k = 0; k < 4; k++) {
        int f = k * 256 + tx;
        int node = f >> 4;
        if (node < nrem)
            *reinterpret_cast<float4*>(&xs[node][(f & 15) * 4]) = gp[f];
    }
    __syncthreads();

    int q = tx & 3;
    int nn = tx >> 2;
    float4 acc = make_float4(0.f, 0.f, 0.f, 0.f);
#pragma unroll
    for (int c4 = 0; c4 < 16; c4++) {
        float4 xA = *reinterpret_cast<const float4*>(&xs[nn][c4 * 4]);
        float4 w0 = *reinterpret_cast<const float4*>(&w[c4 * 4 + 0][q * 4]);
        float4 w1 = *reinterpret_cast<const float4*>(&w[c4 * 4 + 1][q * 4]);
        float4 w2 = *reinterpret_cast<const float4*>(&w[c4 * 4 + 2][q * 4]);
        float4 w3 = *reinterpret_cast<const float4*>(&w[c4 * 4 + 3][q * 4]);
        acc.x += xA.x * w0.x + xA.y * w1.x + xA.z * w2.x + xA.w * w3.x;
        acc.y += xA.x * w0.y + xA.y * w1.y + xA.z * w2.y + xA.w * w3.y;
        acc.z += xA.x * w0.z + xA.y * w1.z + xA.z * w2.z + xA.w * w3.z;
        acc.w += xA.x * w0.w + xA.y * w1.w + xA.z * w2.w + xA.w * w3.w;
    }

    float el = acc.x * al[q * 4] + acc.y * al[q * 4 + 1] + acc.z * al[q * 4 + 2] + acc.w * al[q * 4 + 3];
    float er = acc.x * ar[q * 4] + acc.y * ar[q * 4 + 1] + acc.z * ar[q * 4 + 2] + acc.w * ar[q * 4 + 3];
    el += __shfl_xor(el, 1); el += __shfl_xor(el, 2);
    er += __shfl_xor(er, 1); er += __shfl_xor(er, 2);

    if (nn < nrem) {
        __half* hb = hs1x + ((size_t)t * N_SRC + n0) * RW;
        H4 pk;
        pk.a = __floats2half2_rn(acc.x, acc.y);
        pk.b = __floats2half2_rn(acc.z, acc.w);
        *reinterpret_cast<H4*>(hb + (size_t)nn * RW + q * 4) = pk;
        if (q == 0) {
            *reinterpret_cast<float*>(hb + (size_t)nn * RW + 16) = el;
            int n = n0 + nn;
            if (n < N_DST1) er1[(size_t)t * N_DST1 + n] = er;
        }
    }
}

// ---------------- CSR build: parallel hist + scan (+wvec) ---------------
__global__ __launch_bounds__(256) void k_hist(
    const int* __restrict__ d1, const int* __restrict__ d2,
    int* __restrict__ cnt1, int* __restrict__ cnt2)
{
    int e = blockIdx.x * 256 + threadIdx.x;
    if (e < E1) atomicAdd(&cnt1[d1[e]], 1);
    else if (e < E1 + E2) atomicAdd(&cnt2[d2[e - E1]], 1);
}

__device__ void scan_one(const int* cnt, int* off, int* cur, int N)
{
    __shared__ int part[1024];
    int tx = threadIdx.x;
    int CH = (N + 1023) / 1024;
    int base = tx * CH;
    int p = 0;
    for (int k = 0; k < CH; k++) { int i = base + k; if (i < N) p += cnt[i]; }
    part[tx] = p;
    __syncthreads();
#pragma unroll
    for (int d = 1; d < 1024; d <<= 1) {
        int v = (tx >= d) ? part[tx - d] : 0;
        __syncthreads();
        part[tx] += v;
        __syncthreads();
    }
    int run = (tx == 0) ? 0 : part[tx - 1];
    if (tx == 0) off[0] = 0;
    for (int k = 0; k < CH; k++) {
        int i = base + k;
        if (i < N) { cur[i] = run; run += cnt[i]; off[i + 1] = run; }
    }
}

__global__ __launch_bounds__(1024) void k_scan(
    const int* __restrict__ cnt1, int* __restrict__ off1, int* __restrict__ cur1,
    const int* __restrict__ cnt2, int* __restrict__ off2, int* __restrict__ cur2,
    const float* __restrict__ W2, const float* __restrict__ al2,
    const float* __restrict__ ar2, float* __restrict__ wl2, float* __restrict__ wr2)
{
    if (blockIdx.x == 2) {
        int tx = threadIdx.x;
        if (tx < 32) {
            int c = tx & 15;
            const float* a = (tx < 16) ? al2 : ar2;
            float s = 0.f;
            for (int o = 0; o < C_OUT; o++) s += W2[c * C_OUT + o] * a[o];
            if (tx < 16) wl2[c] = s; else wr2[c] = s;
        }
        return;
    }
    if (blockIdx.x == 0) scan_one(cnt1, off1, cur1, N_DST1);
    else                 scan_one(cnt2, off2, cur2, N_DST2);
}

__global__ __launch_bounds__(256) void k_scatter(
    const int* __restrict__ s1, const int* __restrict__ d1, const float* __restrict__ w1,
    int* __restrict__ cur1, int2* __restrict__ sw1,
    const int* __restrict__ s2, const int* __restrict__ d2, const float* __restrict__ w2,
    int* __restrict__ cur2, int2* __restrict__ sw2)
{
    int e = blockIdx.x * 256 + threadIdx.x;
    if (e < E1) {
        int d = d1[e];
        int p = atomicAdd(&cur1[d], 1);
        sw1[p] = make_int2(s1[e], __float_as_int(w1[e]));
    } else if (e < E1 + E2) {
        int ee = e - E1;
        int d = d2[ee];
        int p = atomicAdd(&cur2[d], 1);
        sw2[p] = make_int2(s2[ee], __float_as_int(w2[ee]));
    }
}

// ---------------- fused GAT layer: 16 lanes per (dst,t) -----------------
// lane16 = eslot*4 + q. 4/2/1 independent gather chains. Both layers read
// packed 40B rows (el folded into the h-row: ~1.5 lines/edge vs 2).
// !FINAL writes the packed h1 row (fp16 h + fp32 el2) for layer 2.
// No max shift: logits bounded (~[-1,4] for this model), den >= ~6.
template <int NDST, int NSRC, bool FINAL>
__global__ __launch_bounds__(256) void k_gat(
    const int* __restrict__ off, const int2* __restrict__ sw,
    const float* __restrict__ er,
    const __half* __restrict__ hs, void* __restrict__ outp,
    const float* __restrict__ wl, const float* __restrict__ wr,
    float* __restrict__ er_out)
{
    __shared__ float w2s[FINAL ? HID * C_OUT : 1];
    int tx = threadIdx.x;
    if (FINAL) {
        for (int idx = tx; idx < HID * C_OUT; idx += 256) w2s[idx] = wl[idx];
        __syncthreads();
    }
    int wblk = xcd_swizzle(blockIdx.x, (NDST * T) / 16);
    int grp = tx >> 4;
    int lane16 = tx & 15;
    int q = lane16 & 3;
    int eslot = lane16 >> 2;
    int g = wblk * 16 + grp;       // t*NDST + d
    int t = g / NDST;
    int d = g - t * NDST;
    int start = off[d], end = off[d + 1];
    float erv = er[g];
    const __half* hsb = hs + (size_t)t * NSRC * RW;

    float4 num = make_float4(0.f, 0.f, 0.f, 0.f);
    float den = 0.f;
    int i = start + eslot;
    for (; i + 12 < end; i += 16) {   // 4 independent chains
        int2 sa = sw[i];
        int2 sb = sw[i + 4];
        int2 sc = sw[i + 8];
        int2 sd = sw[i + 12];
        float ea, eb, ec, ed;
        float4 ha, hb, hc, hd;
        edge_load(hsb, sa.x, q, ea, ha);
        edge_load(hsb, sb.x, q, eb, hb);
        edge_load(hsb, sc.x, q, ec, hc);
        edge_load(hsb, sd.x, q, ed, hd);
        float exa = __expf(lrelu(ea + erv, 0.2f));
        float exb = __expf(lrelu(eb + erv, 0.2f));
        float exc = __expf(lrelu(ec + erv, 0.2f));
        float exd = __expf(lrelu(ed + erv, 0.2f));
        den += (exa + exb) + (exc + exd);
        float ca = exa * __int_as_float(sa.y);
        float cb = exb * __int_as_float(sb.y);
        float cc = exc * __int_as_float(sc.y);
        float cd = exd * __int_as_float(sd.y);
        num.x += ca * ha.x + cb * hb.x + cc * hc.x + cd * hd.x;
        num.y += ca * ha.y + cb * hb.y + cc * hc.y + cd * hd.y;
        num.z += ca * ha.z + cb * hb.z + cc * hc.z + cd * hd.z;
        num.w += ca * ha.w + cb * hb.w + cc * hc.w + cd * hd.w;
    }
    for (; i + 4 < end; i += 8) {     // 2 independent chains
        int2 sa = sw[i];
        int2 sb = sw[i + 4];
        float ea, eb;
        float4 ha, hb;
        edge_load(hsb, sa.x, q, ea, ha);
        edge_load(hsb, sb.x, q, eb, hb);
        float exa = __expf(lrelu(ea + erv, 0.2f));
        float exb = __expf(lrelu(eb + erv, 0.2f));
        den += exa + exb;
        float ca = exa * __int_as_float(sa.y);
        float cb = exb * __int_as_float(sb.y);
        num.x += ca * ha.x + cb * hb.x;
        num.y += ca * ha.y + cb * hb.y;
        num.z += ca * ha.z + cb * hb.z;
        num.w += ca * ha.w + cb * hb.w;
    }
    if (i < end) {
        int2 sa = sw[i];
        float ea;
        float4 ha;
        edge_load(hsb, sa.x, q, ea, ha);
        float exa = __expf(lrelu(ea + erv, 0.2f));
        den += exa;
        float ca = exa * __int_as_float(sa.y);
        num.x += ca * ha.x; num.y += ca * ha.y;
        num.z += ca * ha.z; num.w += ca * ha.w;
    }
#pragma unroll
    for (int mk = 4; mk <= 8; mk <<= 1) {
        num.x += __shfl_xor(num.x, mk);
        num.y += __shfl_xor(num.y, mk);
        num.z += __shfl_xor(num.z, mk);
        num.w += __shfl_xor(num.w, mk);
        den   += __shfl_xor(den, mk);
    }
    float inv = 1.f / (den + 1e-9f);
    float4 v = make_float4(num.x * inv, num.y * inv, num.z * inv, num.w * inv);

    if (!FINAL) {
        v.x = lrelu(v.x, 0.01f); v.y = lrelu(v.y, 0.01f);
        v.z = lrelu(v.z, 0.01f); v.w = lrelu(v.w, 0.01f);
        if (eslot == 0) {
            // packed h1 row: fp16 h quarters + fp32 el2
            __half* hb = (__half*)outp + (size_t)g * RW;
            H4 pk;
            pk.a = __floats2half2_rn(v.x, v.y);
            pk.b = __floats2half2_rn(v.z, v.w);
            *reinterpret_cast<H4*>(hb + q * 4) = pk;
            float pl = v.x * wl[q * 4] + v.y * wl[q * 4 + 1] + v.z * wl[q * 4 + 2] + v.w * wl[q * 4 + 3];
            float pr = v.x * wr[q * 4] + v.y * wr[q * 4 + 1] + v.z * wr[q * 4 + 2] + v.w * wr[q * 4 + 3];
            pl += __shfl_xor(pl, 1); pl += __shfl_xor(pl, 2);
            pr += __shfl_xor(pr, 1); pr += __shfl_xor(pr, 2);
            if (q == 0) {
                *reinterpret_cast<float*>(hb + 16) = pl;
                if (d < N_DST2) er_out[(size_t)t * N_DST2 + d] = pr;
            }
        }
    } else {
        float4 v1, v2, v3;
        v1.x = __shfl_xor(v.x, 1); v1.y = __shfl_xor(v.y, 1); v1.z = __shfl_xor(v.z, 1); v1.w = __shfl_xor(v.w, 1);
        v2.x = __shfl_xor(v.x, 2); v2.y = __shfl_xor(v.y, 2); v2.z = __shfl_xor(v.z, 2); v2.w = __shfl_xor(v.w, 2);
        v3.x = __shfl_xor(v.x, 3); v3.y = __shfl_xor(v.y, 3); v3.z = __shfl_xor(v.z, 3); v3.w = __shfl_xor(v.w, 3);
        int obase = q * 8;
        float out8[8];
#pragma unroll
        for (int oo = 0; oo < 8; oo++) out8[oo] = 0.f;
#define ACCQ(Q, R0)                                                             \
        {                                                                       \
            int r0 = (R0) * 4;                                                  \
            _Pragma("unroll")                                                   \
            for (int oo = 0; oo < 8; oo++)                                      \
                out8[oo] += (Q).x * w2s[(r0 + 0) * C_OUT + obase + oo]          \
                          + (Q).y * w2s[(r0 + 1) * C_OUT + obase + oo]          \
                          + (Q).z * w2s[(r0 + 2) * C_OUT + obase + oo]          \
                          + (Q).w * w2s[(r0 + 3) * C_OUT + obase + oo];         \
        }
        ACCQ(v,  q);
        ACCQ(v1, q ^ 1);
        ACCQ(v2, q ^ 2);
        ACCQ(v3, q ^ 3);
#undef ACCQ
        if (eslot == 0) {
            float* op = (float*)outp + (size_t)g * C_OUT + obase;
            float4 w0 = make_float4(lrelu(out8[0], 0.01f), lrelu(out8[1], 0.01f),
                                    lrelu(out8[2], 0.01f), lrelu(out8[3], 0.01f));
            float4 w1 = make_float4(lrelu(out8[4], 0.01f), lrelu(out8[5], 0.01f),
                                    lrelu(out8[6], 0.01f), lrelu(out8[7], 0.01f));
            *reinterpret_cast<float4*>(op) = w0;
            *reinterpret_cast<float4*>(op + 4) = w1;
        }
    }
}

extern "C" void kernel_launch(void* const* d_in, const int* in_sizes, int n_in,
                              void* d_out, int out_size, void* d_ws, size_t ws_size,
                              hipStream_t stream)
{
    const float* node_feat = (const float*)d_in[0];
    const int*   esrc1     = (const int*)d_in[1];
    const int*   edst1     = (const int*)d_in[2];
    const float* ew1       = (const float*)d_in[3];
    const int*   esrc2     = (const int*)d_in[4];
    const int*   edst2     = (const int*)d_in[5];
    const float* ew2       = (const float*)d_in[6];
    const float* W1        = (const float*)d_in[7];
    const float* a_l1      = (const float*)d_in[8];
    const float* a_r1      = (const float*)d_in[9];
    const float* W2        = (const float*)d_in[10];
    const float* a_l2      = (const float*)d_in[11];
    const float* a_r2      = (const float*)d_in[12];
    float* out = (float*)d_out;

    float* ws = (float*)d_ws;
    __half* hs1x = (__half*)ws;             // T*N_SRC*RW halfs = 24MB (packed)
    float* er1 = ws + 6000000;              //   240,000  [T][N_DST1]
    __half* h1x = (__half*)(er1 + 240000);  // T*N_DST1*RW halfs = 9.6MB (packed)
    float* er2 = er1 + 240000 + 2400000;    //   120,000  [T][N_DST2]
    float* wl2 = er2 + 120000;              //        16
    float* wr2 = wl2 + 16;                  //        16
    int2* sw1 = (int2*)(wr2 + 16);          // E1 (16B-aligned)
    int2* sw2 = sw1 + E1;                   // E2
    int* cnt1 = (int*)(sw2 + E2);           //  20,000 (16B-aligned)
    int* cnt2 = cnt1 + N_DST1;              //  10,000
    int* off1 = cnt2 + N_DST2;              //  20,001
    int* cur1 = off1 + N_DST1 + 1;          //  20,000
    int* off2 = cur1 + N_DST1;              //  10,001
    int* cur2 = off2 + N_DST2 + 1;          //  10,000

    k_zero<<<30, 256, 0, stream>>>((int4*)cnt1, (N_DST1 + N_DST2) / 4);
    k_hist<<<(E1 + E2 + 255) / 256, 256, 0, stream>>>(edst1, edst2, cnt1, cnt2);
    k_scan<<<3, 1024, 0, stream>>>(cnt1, off1, cur1, cnt2, off2, cur2,
                                   W2, a_l2, a_r2, wl2, wr2);
    k_scatter<<<(E1 + E2 + 255) / 256, 256, 0, stream>>>(
        esrc1, edst1, ew1, cur1, sw1,
        esrc2, edst2, ew2, cur2, sw2);

    {
        dim3 g((N_SRC + 63) / 64, T);
        k_transform1<<<g, 256, 0, stream>>>(node_feat, W1, a_l1, a_r1, hs1x, er1);
    }
    k_gat<N_DST1, N_SRC, false><<<(N_DST1 * T) / 16, 256, 0, stream>>>(
        off1, sw1, er1, hs1x, h1x, wl2, wr2, er2);
    k_gat<N_DST2, N_DST1, true><<<(N_DST2 * T) / 16, 256, 0, stream>>>(
        off2, sw2, er2, h1x, out, W2, nullptr, nullptr);
}